// Round 10
// baseline (100.786 us; speedup 1.0000x reference)
//
#include <hip/hip_runtime.h>

// state[e, g, t, c] = sum_{s<=t} param_1 * disp[e, s]
// -> cumsum over t (T=128), broadcast over g (8) and c (6).
// Output [E, 8, 128, 6] fp32: write-bound (491.5 MB writes vs 10.2 MB reads).
// Ledger: plain-store structures (R1/R4/R6/R7/R9) all 97-102 us.
//   R3: NT stores, interleaved with LDS reads: 95.4 us, PASSED post-timing.
//   R5: NT stores, 6-deep register burst: FAILED post-timing revalidation.
//   R8/R9: phase-separated reads + perfect balance: 97.2 us.
// R10: NT + phase-separation combined, with R3-style store interleave
//      (val recomputed from LDS per g-block; memory clobber stops the
//      compiler from clumping stores into R5's burst pattern).

#define T_LEN 128
#define PER_ELEM (8 * T_LEN * 6)       // 6144 floats per element
#define NBLK 1250
#define WPB  4                          // waves per block (256 threads)
#define NWAVES (NBLK * WPB)             // 5000 waves
#define ITERS 4                         // 20000 / 5000 exactly

typedef float f32x4 __attribute__((ext_vector_type(4)));

__global__ __launch_bounds__(256) void state_cumsum_bcast(
    const float* __restrict__ disp,    // [E, 128]
    const float* __restrict__ param1,  // [1]
    float* __restrict__ out,           // [E, 8, 128, 6]
    int n_elem) {
  __shared__ float cum[WPB][T_LEN];    // per-wave private slice: no barriers

  const int tid  = threadIdx.x;
  const int wv   = tid >> 6;
  const int lane = tid & 63;
  const int wave_id = blockIdx.x * WPB + wv;
  const float p = param1[0];

  // ---- READ PHASE: all owned elements' disp loads issued back-to-back ----
  float a0[ITERS], a1[ITERS];
  #pragma unroll
  for (int k = 0; k < ITERS; ++k) {
    const int e = wave_id + k * NWAVES;
    if (e < n_elem) {
      a0[k] = disp[(size_t)e * T_LEN + lane];        // coalesced 256B
      a1[k] = disp[(size_t)e * T_LEN + 64 + lane];
    } else {
      a0[k] = 0.f; a1[k] = 0.f;
    }
  }
  __builtin_amdgcn_sched_barrier(0);   // all reads issue before write phase

  // ---- WRITE PHASE: scan + broadcast, zero further global reads ----
  #pragma unroll
  for (int k = 0; k < ITERS; ++k) {
    const int e = wave_id + k * NWAVES;
    if (e >= n_elem) break;

    // inclusive scan across 64 lanes, two segments cover T=128
    float x0 = p * a0[k], x1 = p * a1[k];
    #pragma unroll
    for (int d = 1; d < 64; d <<= 1) {
      float y0 = __shfl_up(x0, d, 64);
      float y1 = __shfl_up(x1, d, 64);
      if (lane >= d) { x0 += y0; x1 += y1; }
    }
    const float total0 = __shfl(x0, 63, 64);
    cum[wv][lane]      = x0;
    cum[wv][64 + lane] = x1 + total0;  // wave-local LDS: lgkmcnt orders it

    // 8 identical g-blocks of 768 floats (192 float4, 3 per lane).
    // Recompute val from LDS inside the g-loop (R3's passing pattern):
    // keeps NT stores interleaved with LDS reads instead of a 24-burst.
    f32x4* o4 = reinterpret_cast<f32x4*>(out + (size_t)e * PER_ELEM);
    #pragma unroll
    for (int g = 0; g < 8; ++g) {
      asm volatile("" ::: "memory");   // stop cross-g hoist/clump of stores
      #pragma unroll
      for (int i = 0; i < 3; ++i) {
        const int f = 4 * (i * 64 + lane);   // t = f/6 < 128
        f32x4 w;
        w.x = cum[wv][(f + 0) / 6];
        w.y = cum[wv][(f + 1) / 6];
        w.z = cum[wv][(f + 2) / 6];
        w.w = cum[wv][(f + 3) / 6];
        __builtin_nontemporal_store(w, &o4[g * 192 + i * 64 + lane]);
      }
    }
  }
}

extern "C" void kernel_launch(void* const* d_in, const int* in_sizes, int n_in,
                              void* d_out, int out_size, void* d_ws, size_t ws_size,
                              hipStream_t stream) {
  const float* disp   = (const float*)d_in[0];  // [E, 128]
  const float* param1 = (const float*)d_in[1];  // [1]
  float* out = (float*)d_out;

  const int n_elem = in_sizes[0] / T_LEN;       // 20000

  state_cumsum_bcast<<<NBLK, 256, 0, stream>>>(disp, param1, out, n_elem);
}